// Round 4
// baseline (618.454 us; speedup 1.0000x reference)
//
#include <hip/hip_runtime.h>

typedef unsigned short u16;
typedef unsigned int u32;

typedef __bf16 bfrag __attribute__((ext_vector_type(8)));   // 8 bf16 = 4 VGPRs (MFMA A/B operand)
typedef float f32x4 __attribute__((ext_vector_type(4)));    // MFMA C/D operand

// ---------- bf16 helpers ----------
__device__ __forceinline__ float b2f(u16 h) {
    u32 u = ((u32)h) << 16;
    return __builtin_bit_cast(float, u);
}
__device__ __forceinline__ u16 f2b(float f) {   // RNE
    u32 u = __builtin_bit_cast(u32, f);
    u += 0x7fffu + ((u >> 16) & 1u);
    return (u16)(u >> 16);
}
// pack two floats to bf16 pair (round-half-up; fine for attention P weights)
__device__ __forceinline__ u32 pack2(float lo, float hi) {
    u32 a = __builtin_bit_cast(u32, lo) + 0x8000u;
    u32 b = __builtin_bit_cast(u32, hi) + 0x8000u;
    return (a >> 16) | (b & 0xffff0000u);
}

// ---------- fast exp2 ----------
#if defined(__has_builtin)
#if __has_builtin(__builtin_amdgcn_exp2f)
#define EXP2(x) __builtin_amdgcn_exp2f(x)
#endif
#endif
#ifndef EXP2
#define EXP2(x) exp2f(x)
#endif

// ---------- async global->LDS (width 16), with fallback ----------
#if defined(__has_builtin)
#if __has_builtin(__builtin_amdgcn_global_load_lds)
#define HAS_GLL 1
#endif
#endif
#ifndef HAS_GLL
#define HAS_GLL 0
#endif

#if HAS_GLL
typedef __attribute__((address_space(1))) const u32 as1_u32;
typedef __attribute__((address_space(3))) u32 as3_u32;
__device__ __forceinline__ void gl_lds16(const u16* g, u16* l) {
    __builtin_amdgcn_global_load_lds((as1_u32*)g, (as3_u32*)l, 16, 0, 0);
}
#endif

// Problem constants
#define BATCH 4
#define SEQ   2048
#define DM    1024
#define NH    16
#define HD    64
#define MB    32
#define STOK  (BATCH * SEQ)   // 8192
#define QKVW  (3 * DM)        // 3072: fused QKV row width

// log2(e)/sqrt(32): folded into q_enc so scores exponentiate via exp2 directly
#define QSCALE 0.25503524337503433f

// ---------- epilogue store helpers ----------
__device__ __forceinline__ void storeC(u16* C, size_t idx, float v)   { C[idx] = f2b(v); }
__device__ __forceinline__ void storeC(float* C, size_t idx, float v) { C[idx] = v; }

// =====================================================================
// fp32 -> bf16 conversion kernels (one-shot prepass; memory-bound)
// =====================================================================
__global__ __launch_bounds__(256) void cvt_f32_bf16(
    const float* __restrict__ s, u16* __restrict__ d, int n8)
{
    int i = blockIdx.x * 256 + threadIdx.x;
    if (i >= n8) return;
    const float4* sp = (const float4*)s + (size_t)i * 2;
    float4 a = sp[0], b = sp[1];
    u16 t[8] = { f2b(a.x), f2b(a.y), f2b(a.z), f2b(a.w),
                 f2b(b.x), f2b(b.y), f2b(b.z), f2b(b.w) };
    ((uint4*)d)[i] = *(uint4*)t;
}

__global__ __launch_bounds__(256) void cvt3_f32_bf16(
    const float* __restrict__ a, const float* __restrict__ b,
    const float* __restrict__ c, u16* __restrict__ d, int n8)
{
    const float* s = (blockIdx.y == 0) ? a : ((blockIdx.y == 1) ? b : c);
    u16* dd = d + (size_t)blockIdx.y * n8 * 8;
    int i = blockIdx.x * 256 + threadIdx.x;
    if (i >= n8) return;
    const float4* sp = (const float4*)s + (size_t)i * 2;
    float4 x = sp[0], y = sp[1];
    u16 t[8] = { f2b(x.x), f2b(x.y), f2b(x.z), f2b(x.w),
                 f2b(y.x), f2b(y.y), f2b(y.z), f2b(y.w) };
    ((uint4*)dd)[i] = *(uint4*)t;
}

// =====================================================================
// GEMM: C[M,N] = A[M,K] @ Bt[N,K]^T   (bf16 in, fp32 acc)
// m97-style: 128x128 tile, BK=32, global_load_lds width-16 staging.
// =====================================================================
template <typename TC>
__global__ __launch_bounds__(256) void gemm_bt(
    const u16* __restrict__ A, const u16* __restrict__ Bt, TC* __restrict__ C,
    int M, int Nc, int K)
{
    __shared__ alignas(16) u16 As[128 * 32];
    __shared__ alignas(16) u16 Bs[128 * 32];

    const int tid  = threadIdx.x;
    const int wave = tid >> 6;
    const int lane = tid & 63;
    const int quad = lane >> 4;
    const int lrow = lane & 15;
    const int bm = blockIdx.y * 128;
    const int bn = blockIdx.x * 128;
    const int wm = (wave & 1) * 64;
    const int wn = (wave >> 1) * 64;

    f32x4 acc[4][4] = {};

    for (int k0 = 0; k0 < K; k0 += 32) {
#if HAS_GLL
        for (int p = 0; p < 2; ++p) {
            int cbase = wave * 128 + p * 64;       // wave-uniform
            int cme   = cbase + lane;
            int row = cme >> 2, col = (cme & 3) * 8;
            gl_lds16(&A [(size_t)(bm + row) * K + k0 + col], &As[(size_t)cbase * 8]);
            gl_lds16(&Bt[(size_t)(bn + row) * K + k0 + col], &Bs[(size_t)cbase * 8]);
        }
#else
        for (int p = 0; p < 2; ++p) {
            int idx = p * 256 + tid, row = idx >> 2, col = (idx & 3) * 8;
            *(uint4*)&As[row * 32 + col] = *(const uint4*)&A [(size_t)(bm + row) * K + k0 + col];
            *(uint4*)&Bs[row * 32 + col] = *(const uint4*)&Bt[(size_t)(bn + row) * K + k0 + col];
        }
#endif
        __syncthreads();

        bfrag af[4], bfv[4];
        for (int i = 0; i < 4; ++i)
            af[i] = *(const bfrag*)&As[(wm + i * 16 + lrow) * 32 + quad * 8];
        for (int j = 0; j < 4; ++j)
            bfv[j] = *(const bfrag*)&Bs[(wn + j * 16 + lrow) * 32 + quad * 8];

        for (int i = 0; i < 4; ++i)
            for (int j = 0; j < 4; ++j)
                acc[i][j] = __builtin_amdgcn_mfma_f32_16x16x32_bf16(af[i], bfv[j], acc[i][j], 0, 0, 0);
        __syncthreads();
    }

    for (int i = 0; i < 4; ++i)
        for (int j = 0; j < 4; ++j)
            for (int r = 0; r < 4; ++r) {
                int row = bm + wm + i * 16 + quad * 4 + r;
                int col = bn + wn + j * 16 + lrow;
                storeC(C, (size_t)row * Nc + col, acc[i][j][r]);
            }
}

// =====================================================================
// Encode: enc[s,h,m] = tanh( sum_d QKV[s, off+h*64+d] * W_enc[h,d,m] )
// q_enc is PRE-SCALED by QSCALE (folds softmax scale + log2e into encode).
// grid (8192, 2): y=0 -> Q cols -> q_enc, y=1 -> K cols -> k_enc.
// =====================================================================
__global__ __launch_bounds__(512) void encode_kernel(
    const u16* __restrict__ QKV, const float* __restrict__ Wenc,
    u16* __restrict__ qe, u16* __restrict__ ke)
{
    const int isK = blockIdx.y;
    const u16* src = QKV + (size_t)blockIdx.x * QKVW + (isK ? DM : 0);
    u16* dst       = (isK ? ke : qe) + (size_t)blockIdx.x * (NH * MB);
    const int h = threadIdx.x >> 5;
    const int m = threadIdx.x & 31;

    __shared__ float xrow[DM];
    for (int i = threadIdx.x; i < DM; i += 512)
        xrow[i] = b2f(src[i]);
    __syncthreads();

    const float* w = &Wenc[h * (HD * MB) + m];
    const float* xh = &xrow[h * HD];
    float acc = 0.f;
    for (int d = 0; d < HD; ++d)
        acc += xh[d] * w[d * MB];

    float e = __expf(2.f * acc);
    float t = 1.f - 2.f / (e + 1.f);
    if (!isK) t *= QSCALE;
    dst[h * MB + m] = f2b(t);
}

// =====================================================================
// Transpose V cols of QKV [S, 3072] -> Vt [B*H*64, 2048]
// =====================================================================
__global__ __launch_bounds__(256) void transpose_v(
    const u16* __restrict__ QKV, u16* __restrict__ Vt)
{
    const int nt = blockIdx.x, h = blockIdx.y, b = blockIdx.z;
    __shared__ alignas(16) u16 tile[64][72];
    const int tid = threadIdx.x;

    for (int p = 0; p < 2; ++p) {
        int idx = p * 256 + tid;
        int t  = idx >> 3;
        int dc = (idx & 7) * 8;
        *(uint4*)&tile[t][dc] =
            *(const uint4*)&QKV[(size_t)(b * SEQ + nt * 64 + t) * QKVW + 2 * DM + h * HD + dc];
    }
    __syncthreads();
    for (int p = 0; p < 2; ++p) {
        int idx = p * 256 + tid;
        int d  = idx >> 3;
        int tc = (idx & 7) * 8;
        u16 tmp[8];
        for (int j = 0; j < 8; ++j) tmp[j] = tile[tc + j][d];
        *(uint4*)&Vt[(size_t)((b * NH + h) * HD + d) * SEQ + nt * 64 + tc] = *(uint4*)tmp;
    }
}

// =====================================================================
// Flash attention v3: wave-private 16 queries x ALL 2048 keys.
// - No cross-wave combine, no __syncthreads, tiny LDS (8KB/block).
// - q_enc pre-scaled -> P = exp2(St) directly (no mul).
// - den accumulated via MFMA with all-ones B: lands lane-exact in store layout.
// - P LDS round-trip uses XOR swizzle (chunk-of-8 ^ lrow&7): bank-minimum
//   b64 writes and b128 reads (verified by bank arithmetic).
// grid (h, b, qt): blocks sharing (b,h)'s ke/Vt slices co-locate per XCD (h%8).
// =====================================================================
#define PROW 64   // P row stride in u16 (64-key chunk, no pad needed w/ swizzle)

__global__ __launch_bounds__(256) void flash_attn(
    const u16* __restrict__ qe,   // [S, 512], pre-scaled
    const u16* __restrict__ ke,   // [S, 512]
    const u16* __restrict__ Vt,   // [B*H*64, 2048]
    u16* __restrict__ AO)         // [S, 1024]
{
    const int h = blockIdx.x, b = blockIdx.y, qt = blockIdx.z;
    const int tid  = threadIdx.x;
    const int wave = tid >> 6;
    const int lane = tid & 63;
    const int quad = lane >> 4;
    const int lrow = lane & 15;

    __shared__ alignas(16) u16 Plds[4][16 * PROW];  // 8 KB total

    const int s0 = b * SEQ + qt * 64;   // block query base
    const int q0 = wave * 16;           // wave query offset within block

    // q_enc B-frag: B[n=q=lrow][k=mbit=quad*8+j]
    bfrag qf = *(const bfrag*)&qe[(size_t)(s0 + q0 + lrow) * (NH * MB) + h * MB + quad * 8];

    const u16* keb = ke + (size_t)(b * SEQ) * (NH * MB) + h * MB + quad * 8;
    const u16* vtb = Vt + (size_t)((b * NH + h) * HD) * SEQ;
    u16* myP = Plds[wave];
    const int sw = lrow & 7;            // XOR swizzle key

    const bfrag ones = __builtin_bit_cast(bfrag,
        (uint4){0x3f803f80u, 0x3f803f80u, 0x3f803f80u, 0x3f803f80u});
    const f32x4 zero = {0.f, 0.f, 0.f, 0.f};

    f32x4 O[4] = {};    // D[q=quad*4+r][d=j*16+lrow]
    f32x4 den = {};     // same row layout, cols all-equal

    for (int c = 0; c < 32; ++c) {
        const int k0 = c * 64;

        // k_enc A-frags: rows = keys k0 + t*16 + lrow
        bfrag kf[4];
        for (int t = 0; t < 4; ++t)
            kf[t] = *(const bfrag*)&keb[(size_t)(k0 + t * 16 + lrow) * (NH * MB)];
        // V B-frags straight from global: rows = d, k = keys (two 32-halves)
        bfrag vf[8];
        for (int j = 0; j < 4; ++j)
            for (int hh = 0; hh < 2; ++hh)
                vf[j * 2 + hh] = *(const bfrag*)&vtb[(size_t)(j * 16 + lrow) * SEQ
                                                     + k0 + hh * 32 + quad * 8];

        // St[t]: D[key = t*16+quad*4+r][q = lrow], already log2-scaled
        f32x4 St[4];
        for (int t = 0; t < 4; ++t)
            St[t] = __builtin_amdgcn_mfma_f32_16x16x32_bf16(kf[t], qf, zero, 0, 0, 0);

        // P = 2^St -> packed b64 LDS write at swizzled chunk
        for (int t = 0; t < 4; ++t) {
            float e0 = EXP2(St[t][0]);
            float e1 = EXP2(St[t][1]);
            float e2 = EXP2(St[t][2]);
            float e3 = EXP2(St[t][3]);
            uint2 pk = { pack2(e0, e1), pack2(e2, e3) };
            int cidx = ((t << 1) | (quad >> 1)) ^ sw;
            *(uint2*)&myP[lrow * PROW + cidx * 8 + (quad & 1) * 4] = pk;
        }

        // pf A-frags: A[q=lrow][k = hh*32 + quad*8 + j]
        bfrag pf[2];
        for (int hh = 0; hh < 2; ++hh) {
            int cidx = ((hh << 2) | quad) ^ sw;
            pf[hh] = *(const bfrag*)&myP[lrow * PROW + cidx * 8];
        }

        // den += P @ ones; O += P @ V
        for (int hh = 0; hh < 2; ++hh)
            den = __builtin_amdgcn_mfma_f32_16x16x32_bf16(pf[hh], ones, den, 0, 0, 0);
        for (int j = 0; j < 4; ++j)
            for (int hh = 0; hh < 2; ++hh)
                O[j] = __builtin_amdgcn_mfma_f32_16x16x32_bf16(pf[hh], vf[j * 2 + hh], O[j], 0, 0, 0);
    }

    // normalize + store: lane holds q = q0+quad*4+r, d = j*16+lrow
    for (int r = 0; r < 4; ++r) {
        float inv = 1.0f / den[r];
        size_t rowbase = (size_t)(s0 + q0 + quad * 4 + r) * DM + h * HD;
        for (int j = 0; j < 4; ++j)
            AO[rowbase + j * 16 + lrow] = f2b(O[j][r] * inv);
    }
}

// =====================================================================
extern "C" void kernel_launch(void* const* d_in, const int* in_sizes, int n_in,
                              void* d_out, int out_size, void* d_ws, size_t ws_size,
                              hipStream_t stream) {
    const float* x    = (const float*)d_in[0];
    const float* Wq   = (const float*)d_in[1];
    const float* Wk   = (const float*)d_in[2];
    const float* Wv   = (const float*)d_in[3];
    const float* Wenc = (const float*)d_in[4];
    const float* Wo   = (const float*)d_in[5];
    float* out = (float*)d_out;

    const size_t MB1 = (size_t)1024 * 1024;
    char* ws = (char*)d_ws;
    // ws: [0:48M) QKV bf16 [8192][3072]; [48:56M) qe; [56:64M) ke
    u16* QKV = (u16*)(ws);
    u16* qe  = (u16*)(ws + 48 * MB1);
    u16* ke  = (u16*)(ws + 56 * MB1);
    // overlays on dead QKV:
    u16* AO   = (u16*)(ws);            // flash out (16M), QKV dead by then
    u16* Wo_b = (u16*)(ws + 16 * MB1); // 2M, written after transpose

    // d_out (32M) as prepass scratch; fully overwritten by final GEMM.
    u16* xb  = (u16*)d_out;                     // 16M bf16 x
    u16* w3b = (u16*)((char*)d_out + 16 * MB1); // 6M: Wq,Wk,Wv rows = Bt [3072][1024]
    u16* Vt  = (u16*)d_out;                     // 16M, written after xb dead

    cvt_f32_bf16<<<dim3(STOK * DM / 8 / 256), 256, 0, stream>>>(x, xb, STOK * DM / 8);
    cvt3_f32_bf16<<<dim3(DM * DM / 8 / 256, 3), 256, 0, stream>>>(Wq, Wk, Wv, w3b, DM * DM / 8);

    // fused QKV projection: [8192,3072] = x @ [Wq;Wk;Wv]^T
    gemm_bt<u16><<<dim3(QKVW / 128, STOK / 128), 256, 0, stream>>>(xb, w3b, QKV, STOK, QKVW, DM);

    encode_kernel<<<dim3(STOK, 2), 512, 0, stream>>>(QKV, Wenc, qe, ke);
    transpose_v<<<dim3(SEQ / 64, NH, BATCH), 256, 0, stream>>>(QKV, Vt);   // overwrites xb (dead)
    cvt_f32_bf16<<<dim3(DM * DM / 8 / 256), 256, 0, stream>>>(Wo, Wo_b, DM * DM / 8);

    flash_attn<<<dim3(NH, BATCH, SEQ / 64), 256, 0, stream>>>(qe, ke, Vt, AO);

    gemm_bt<float><<<dim3(DM / 128, STOK / 128), 256, 0, stream>>>(AO, Wo_b, out, STOK, DM, DM);
}

// Round 5
// 386.126 us; speedup vs baseline: 1.6017x; 1.6017x over previous
//
#include <hip/hip_runtime.h>

typedef unsigned short u16;
typedef unsigned int u32;

typedef __bf16 bfrag __attribute__((ext_vector_type(8)));   // 8 bf16 = 4 VGPRs (MFMA A/B operand)
typedef float f32x4 __attribute__((ext_vector_type(4)));    // MFMA C/D operand

// ---------- bf16 helpers ----------
__device__ __forceinline__ float b2f(u16 h) {
    u32 u = ((u32)h) << 16;
    return __builtin_bit_cast(float, u);
}
__device__ __forceinline__ u16 f2b(float f) {   // RNE
    u32 u = __builtin_bit_cast(u32, f);
    u += 0x7fffu + ((u >> 16) & 1u);
    return (u16)(u >> 16);
}
__device__ __forceinline__ u32 pack2(float lo, float hi) {  // round-half-up
    u32 a = __builtin_bit_cast(u32, lo) + 0x8000u;
    u32 b = __builtin_bit_cast(u32, hi) + 0x8000u;
    return (a >> 16) | (b & 0xffff0000u);
}

// ---------- fast exp2 ----------
#if defined(__has_builtin)
#if __has_builtin(__builtin_amdgcn_exp2f)
#define EXP2(x) __builtin_amdgcn_exp2f(x)
#endif
#endif
#ifndef EXP2
#define EXP2(x) exp2f(x)
#endif

// ---------- async global->LDS (width 16), with fallback ----------
#if defined(__has_builtin)
#if __has_builtin(__builtin_amdgcn_global_load_lds)
#define HAS_GLL 1
#endif
#endif
#ifndef HAS_GLL
#define HAS_GLL 0
#endif

#if HAS_GLL
typedef __attribute__((address_space(1))) const u32 as1_u32;
typedef __attribute__((address_space(3))) u32 as3_u32;
__device__ __forceinline__ void gl_lds16(const u16* g, u16* l) {
    __builtin_amdgcn_global_load_lds((as1_u32*)g, (as3_u32*)l, 16, 0, 0);
}
#endif

// Problem constants
#define BATCH 4
#define SEQ   2048
#define DM    1024
#define NH    16
#define HD    64
#define MB    32
#define STOK  (BATCH * SEQ)   // 8192
#define QKVW  (3 * DM)        // 3072

// log2(e)/sqrt(32): folded into q_enc so P = exp2(S) directly
#define QSCALE 0.25503524337503433f

__device__ __forceinline__ void storeC(u16* C, size_t idx, float v)   { C[idx] = f2b(v); }
__device__ __forceinline__ void storeC(float* C, size_t idx, float v) { C[idx] = v; }

// =====================================================================
// fp32 -> bf16 conversion prepass
// =====================================================================
__global__ __launch_bounds__(256) void cvt_f32_bf16(
    const float* __restrict__ s, u16* __restrict__ d, int n8)
{
    int i = blockIdx.x * 256 + threadIdx.x;
    if (i >= n8) return;
    const float4* sp = (const float4*)s + (size_t)i * 2;
    float4 a = sp[0], b = sp[1];
    u16 t[8] = { f2b(a.x), f2b(a.y), f2b(a.z), f2b(a.w),
                 f2b(b.x), f2b(b.y), f2b(b.z), f2b(b.w) };
    ((uint4*)d)[i] = *(uint4*)t;
}

__global__ __launch_bounds__(256) void cvt3_f32_bf16(
    const float* __restrict__ a, const float* __restrict__ b,
    const float* __restrict__ c, u16* __restrict__ d, int n8)
{
    const float* s = (blockIdx.y == 0) ? a : ((blockIdx.y == 1) ? b : c);
    u16* dd = d + (size_t)blockIdx.y * n8 * 8;
    int i = blockIdx.x * 256 + threadIdx.x;
    if (i >= n8) return;
    const float4* sp = (const float4*)s + (size_t)i * 2;
    float4 x = sp[0], y = sp[1];
    u16 t[8] = { f2b(x.x), f2b(x.y), f2b(x.z), f2b(x.w),
                 f2b(y.x), f2b(y.y), f2b(y.z), f2b(y.w) };
    ((uint4*)dd)[i] = *(uint4*)t;
}

// =====================================================================
// GEMM: C[M,N] = A[M,K] @ Bt[N,K]^T  (m97 structure, unchanged this round)
// =====================================================================
template <typename TC>
__global__ __launch_bounds__(256) void gemm_bt(
    const u16* __restrict__ A, const u16* __restrict__ Bt, TC* __restrict__ C,
    int M, int Nc, int K)
{
    __shared__ alignas(16) u16 As[128 * 32];
    __shared__ alignas(16) u16 Bs[128 * 32];

    const int tid  = threadIdx.x;
    const int wave = tid >> 6;
    const int lane = tid & 63;
    const int quad = lane >> 4;
    const int lrow = lane & 15;
    const int bm = blockIdx.y * 128;
    const int bn = blockIdx.x * 128;
    const int wm = (wave & 1) * 64;
    const int wn = (wave >> 1) * 64;

    f32x4 acc[4][4] = {};

    for (int k0 = 0; k0 < K; k0 += 32) {
#if HAS_GLL
        for (int p = 0; p < 2; ++p) {
            int cbase = wave * 128 + p * 64;       // wave-uniform
            int cme   = cbase + lane;
            int row = cme >> 2, col = (cme & 3) * 8;
            gl_lds16(&A [(size_t)(bm + row) * K + k0 + col], &As[(size_t)cbase * 8]);
            gl_lds16(&Bt[(size_t)(bn + row) * K + k0 + col], &Bs[(size_t)cbase * 8]);
        }
#else
        for (int p = 0; p < 2; ++p) {
            int idx = p * 256 + tid, row = idx >> 2, col = (idx & 3) * 8;
            *(uint4*)&As[row * 32 + col] = *(const uint4*)&A [(size_t)(bm + row) * K + k0 + col];
            *(uint4*)&Bs[row * 32 + col] = *(const uint4*)&Bt[(size_t)(bn + row) * K + k0 + col];
        }
#endif
        __syncthreads();

        bfrag af[4], bfv[4];
        for (int i = 0; i < 4; ++i)
            af[i] = *(const bfrag*)&As[(wm + i * 16 + lrow) * 32 + quad * 8];
        for (int j = 0; j < 4; ++j)
            bfv[j] = *(const bfrag*)&Bs[(wn + j * 16 + lrow) * 32 + quad * 8];

        for (int i = 0; i < 4; ++i)
            for (int j = 0; j < 4; ++j)
                acc[i][j] = __builtin_amdgcn_mfma_f32_16x16x32_bf16(af[i], bfv[j], acc[i][j], 0, 0, 0);
        __syncthreads();
    }

    for (int i = 0; i < 4; ++i)
        for (int j = 0; j < 4; ++j)
            for (int r = 0; r < 4; ++r) {
                int row = bm + wm + i * 16 + quad * 4 + r;
                int col = bn + wn + j * 16 + lrow;
                storeC(C, (size_t)row * Nc + col, acc[i][j][r]);
            }
}

// =====================================================================
// Encode -> PER-HEAD layout: enc[b,h,n,m]  (keys of one head contiguous 64B)
// q_enc pre-scaled by QSCALE. grid (8192, 2): y=0 -> q_enc, y=1 -> k_enc.
// =====================================================================
__global__ __launch_bounds__(512) void encode_kernel(
    const u16* __restrict__ QKV, const float* __restrict__ Wenc,
    u16* __restrict__ qe, u16* __restrict__ ke)
{
    const int isK = blockIdx.y;
    const int s = blockIdx.x;
    const int b = s >> 11, n = s & (SEQ - 1);
    const u16* src = QKV + (size_t)s * QKVW + (isK ? DM : 0);
    u16* dst       = (isK ? ke : qe);
    const int h = threadIdx.x >> 5;
    const int m = threadIdx.x & 31;

    __shared__ float xrow[DM];
    for (int i = threadIdx.x; i < DM; i += 512)
        xrow[i] = b2f(src[i]);
    __syncthreads();

    const float* w = &Wenc[h * (HD * MB) + m];
    const float* xh = &xrow[h * HD];
    float acc = 0.f;
    for (int d = 0; d < HD; ++d)
        acc += xh[d] * w[d * MB];

    float e = __expf(2.f * acc);
    float t = 1.f - 2.f / (e + 1.f);
    if (!isK) t *= QSCALE;
    dst[(size_t)((b * NH + h) * SEQ + n) * MB + m] = f2b(t);
}

// =====================================================================
// Transpose V cols of QKV [S, 3072] -> Vt [B*H*64, 2048]
// =====================================================================
__global__ __launch_bounds__(256) void transpose_v(
    const u16* __restrict__ QKV, u16* __restrict__ Vt)
{
    const int nt = blockIdx.x, h = blockIdx.y, b = blockIdx.z;
    __shared__ alignas(16) u16 tile[64][72];
    const int tid = threadIdx.x;

    for (int p = 0; p < 2; ++p) {
        int idx = p * 256 + tid;
        int t  = idx >> 3;
        int dc = (idx & 7) * 8;
        *(uint4*)&tile[t][dc] =
            *(const uint4*)&QKV[(size_t)(b * SEQ + nt * 64 + t) * QKVW + 2 * DM + h * HD + dc];
    }
    __syncthreads();
    for (int p = 0; p < 2; ++p) {
        int idx = p * 256 + tid;
        int d  = idx >> 3;
        int tc = (idx & 7) * 8;
        u16 tmp[8];
        for (int j = 0; j < 8; ++j) tmp[j] = tile[tc + j][d];
        *(uint4*)&Vt[(size_t)((b * NH + h) * HD + d) * SEQ + nt * 64 + tc] = *(uint4*)tmp;
    }
}

// =====================================================================
// Flash attention v5: block = 128 queries x ALL keys; wave = 32 q (2 frags).
// K-enc & V tiles cooperatively staged in LDS once per block per 64-key chunk
// (coalesced from per-head-contiguous keh / Vt) -- fixes v3's 4x redundant
// scatter-gather global loads. P round-trip stays wave-private in LDS.
// Bank audit (all patterns <=2-way, free): Kt rows pad 40 u16; Vtile/P rows
// pad 72 u16. den via MFMA-with-ones. No __syncthreads in P path.
// grid (h, b, qt): 1024 blocks = 4/CU resident; same-h blocks share an XCD.
// =====================================================================
__global__ __launch_bounds__(256) void flash_attn(
    const u16* __restrict__ qe,   // [B,H,N,32], pre-scaled
    const u16* __restrict__ ke,   // [B,H,N,32]
    const u16* __restrict__ Vt,   // [B*H*64, 2048]
    u16* __restrict__ AO)         // [S, 1024]
{
    const int h = blockIdx.x, b = blockIdx.y, qt = blockIdx.z;
    const int tid  = threadIdx.x;
    const int wave = tid >> 6;
    const int lane = tid & 63;
    const int quad = lane >> 4;
    const int lrow = lane & 15;

    __shared__ alignas(16) u16 Kt[64 * 40];          //  5 KB: [key][mbit] pad 40
    __shared__ alignas(16) u16 Vtile[64 * 72];       //  9 KB: [d][key] pad 72
    __shared__ alignas(16) u16 Plds[8][16 * 72];     // 18 KB: [wave*2+qf][q][key] pad 72

    const size_t bh = (size_t)(b * NH + h);
    const u16* keb = ke + bh * SEQ * MB;
    const u16* qeb = qe + bh * SEQ * MB;
    const u16* vtb = Vt + bh * HD * SEQ;

    const int q0 = qt * 128 + wave * 32;   // wave's first query

    // q_enc B-frags: B[col=q=lrow][k=mbit=quad*8+j] (rows contiguous 64B)
    bfrag qf[2];
    for (int f = 0; f < 2; ++f)
        qf[f] = *(const bfrag*)&qeb[(size_t)(q0 + f * 16 + lrow) * MB + quad * 8];

    u16* myP0 = Plds[wave * 2];
    u16* myP1 = Plds[wave * 2 + 1];

    const bfrag ones = __builtin_bit_cast(bfrag,
        (uint4){0x3f803f80u, 0x3f803f80u, 0x3f803f80u, 0x3f803f80u});
    const f32x4 zero = {0.f, 0.f, 0.f, 0.f};

    f32x4 O[2][4] = {};   // [qf][j]: D[q=quad*4+r][d=j*16+lrow]
    f32x4 den[2] = {};

    for (int c = 0; c < 32; ++c) {
        const int k0 = c * 64;

        __syncthreads();   // protect Kt/Vtile from previous iteration's readers
        // stage K-enc tile: 64 keys x 32 mbits = 4KB, one coalesced pass
        {
            int row = tid >> 2, col = (tid & 3) * 8;
            *(uint4*)&Kt[row * 40 + col] =
                *(const uint4*)&keb[(size_t)(k0 + row) * MB + col];
        }
        // stage V tile: 64 d x 64 keys = 8KB, two passes
        for (int p = 0; p < 2; ++p) {
            int idx = p * 256 + tid;
            int d = idx >> 3, kk = (idx & 7) * 8;
            *(uint4*)&Vtile[d * 72 + kk] =
                *(const uint4*)&vtb[(size_t)d * SEQ + k0 + kk];
        }
        __syncthreads();

        // k_enc A-frags: rows = keys t*16+lrow (shared by both q-frags)
        bfrag kf[4];
        for (int t = 0; t < 4; ++t)
            kf[t] = *(const bfrag*)&Kt[(t * 16 + lrow) * 40 + quad * 8];

        // per q-frag: St = kf @ qf -> P = 2^St -> LDS -> pf
        bfrag pf[2][2];
        for (int f = 0; f < 2; ++f) {
            u16* P = f ? myP1 : myP0;
            f32x4 St[4];
            for (int t = 0; t < 4; ++t)
                St[t] = __builtin_amdgcn_mfma_f32_16x16x32_bf16(kf[t], qf[f], zero, 0, 0, 0);
            // lane holds keys t*16+quad*4..+3 for query lrow
            for (int t = 0; t < 4; ++t) {
                float e0 = EXP2(St[t][0]);
                float e1 = EXP2(St[t][1]);
                float e2 = EXP2(St[t][2]);
                float e3 = EXP2(St[t][3]);
                uint2 pk = { pack2(e0, e1), pack2(e2, e3) };
                *(uint2*)&P[lrow * 72 + t * 16 + quad * 4] = pk;
            }
            for (int hh = 0; hh < 2; ++hh)
                pf[f][hh] = *(const bfrag*)&P[lrow * 72 + hh * 32 + quad * 8];
        }

        // den += P @ ones; O += P @ V  (vf loaded per j from LDS)
        for (int f = 0; f < 2; ++f)
            for (int hh = 0; hh < 2; ++hh)
                den[f] = __builtin_amdgcn_mfma_f32_16x16x32_bf16(pf[f][hh], ones, den[f], 0, 0, 0);
        for (int j = 0; j < 4; ++j) {
            bfrag vf0 = *(const bfrag*)&Vtile[(j * 16 + lrow) * 72 + quad * 8];
            bfrag vf1 = *(const bfrag*)&Vtile[(j * 16 + lrow) * 72 + 32 + quad * 8];
            for (int f = 0; f < 2; ++f) {
                O[f][j] = __builtin_amdgcn_mfma_f32_16x16x32_bf16(pf[f][0], vf0, O[f][j], 0, 0, 0);
                O[f][j] = __builtin_amdgcn_mfma_f32_16x16x32_bf16(pf[f][1], vf1, O[f][j], 0, 0, 0);
            }
        }
    }

    // store: lane holds q = q0 + f*16 + quad*4+r, d = j*16+lrow
    for (int f = 0; f < 2; ++f)
        for (int r = 0; r < 4; ++r) {
            float inv = 1.0f / den[f][r];
            size_t rowbase = (size_t)(b * SEQ + q0 + f * 16 + quad * 4 + r) * DM + h * HD;
            for (int j = 0; j < 4; ++j)
                AO[rowbase + j * 16 + lrow] = f2b(O[f][j][r] * inv);
        }
}

// =====================================================================
extern "C" void kernel_launch(void* const* d_in, const int* in_sizes, int n_in,
                              void* d_out, int out_size, void* d_ws, size_t ws_size,
                              hipStream_t stream) {
    const float* x    = (const float*)d_in[0];
    const float* Wq   = (const float*)d_in[1];
    const float* Wk   = (const float*)d_in[2];
    const float* Wv   = (const float*)d_in[3];
    const float* Wenc = (const float*)d_in[4];
    const float* Wo   = (const float*)d_in[5];
    float* out = (float*)d_out;

    const size_t MB1 = (size_t)1024 * 1024;
    char* ws = (char*)d_ws;
    u16* QKV = (u16*)(ws);            // 48M: [8192][3072]
    u16* qe  = (u16*)(ws + 48 * MB1); // 8M  [B,H,N,32]
    u16* ke  = (u16*)(ws + 56 * MB1); // 8M
    u16* AO   = (u16*)(ws);           // overlays dead QKV
    u16* Wo_b = (u16*)(ws + 16 * MB1);

    u16* xb  = (u16*)d_out;                     // 16M bf16 x (d_out scratch)
    u16* w3b = (u16*)((char*)d_out + 16 * MB1); // 6M [Wq;Wk;Wv] bf16
    u16* Vt  = (u16*)d_out;                     // 16M, after xb dead

    cvt_f32_bf16<<<dim3(STOK * DM / 8 / 256), 256, 0, stream>>>(x, xb, STOK * DM / 8);
    cvt3_f32_bf16<<<dim3(DM * DM / 8 / 256, 3), 256, 0, stream>>>(Wq, Wk, Wv, w3b, DM * DM / 8);

    gemm_bt<u16><<<dim3(QKVW / 128, STOK / 128), 256, 0, stream>>>(xb, w3b, QKV, STOK, QKVW, DM);

    encode_kernel<<<dim3(STOK, 2), 512, 0, stream>>>(QKV, Wenc, qe, ke);
    transpose_v<<<dim3(SEQ / 64, NH, BATCH), 256, 0, stream>>>(QKV, Vt);
    cvt_f32_bf16<<<dim3(DM * DM / 8 / 256), 256, 0, stream>>>(Wo, Wo_b, DM * DM / 8);

    flash_attn<<<dim3(NH, BATCH, SEQ / 128), 256, 0, stream>>>(qe, ke, Vt, AO);

    gemm_bt<float><<<dim3(DM / 128, STOK / 128), 256, 0, stream>>>(AO, Wo_b, out, STOK, DM, DM);
}

// Round 6
// 309.804 us; speedup vs baseline: 1.9963x; 1.2464x over previous
//
#include <hip/hip_runtime.h>

typedef unsigned short u16;
typedef unsigned int u32;

typedef __bf16 bfrag __attribute__((ext_vector_type(8)));   // 8 bf16 = 4 VGPRs (MFMA A/B operand)
typedef float f32x4 __attribute__((ext_vector_type(4)));    // MFMA C/D operand

// ---------- bf16 helpers ----------
__device__ __forceinline__ float b2f(u16 h) {
    u32 u = ((u32)h) << 16;
    return __builtin_bit_cast(float, u);
}
__device__ __forceinline__ u16 f2b(float f) {   // RNE
    u32 u = __builtin_bit_cast(u32, f);
    u += 0x7fffu + ((u >> 16) & 1u);
    return (u16)(u >> 16);
}
// truncating pack (P-weights only: den computed FROM truncated P, so weights
// still sum to exactly 1 -- bias cancels; saves 2 VALU ops per pair)
__device__ __forceinline__ u32 packt(float lo, float hi) {
    return (__builtin_bit_cast(u32, lo) >> 16) | (__builtin_bit_cast(u32, hi) & 0xffff0000u);
}

// ---------- fast exp2 ----------
#if defined(__has_builtin)
#if __has_builtin(__builtin_amdgcn_exp2f)
#define EXP2(x) __builtin_amdgcn_exp2f(x)
#endif
#endif
#ifndef EXP2
#define EXP2(x) exp2f(x)
#endif

// ---------- async global->LDS (width 16), with fallback ----------
#if defined(__has_builtin)
#if __has_builtin(__builtin_amdgcn_global_load_lds)
#define HAS_GLL 1
#endif
#endif
#ifndef HAS_GLL
#define HAS_GLL 0
#endif

#if HAS_GLL
typedef __attribute__((address_space(1))) const u32 as1_u32;
typedef __attribute__((address_space(3))) u32 as3_u32;
__device__ __forceinline__ void gl_lds16(const u16* g, u16* l) {
    // dest: wave-uniform base; HW stores lane's 16B at base + lane*16
    __builtin_amdgcn_global_load_lds((as1_u32*)g, (as3_u32*)l, 16, 0, 0);
}
#endif

// Problem constants
#define BATCH 4
#define SEQ   2048
#define DM    1024
#define NH    16
#define HD    64
#define MB    32
#define STOK  (BATCH * SEQ)   // 8192
#define QKVW  (3 * DM)        // 3072

// log2(e)/sqrt(32): folded into q_enc so P = exp2(S) directly
#define QSCALE 0.25503524337503433f
#define TWOLOG2E 2.8853900817779268f   // 2*log2(e), for tanh via exp2

__device__ __forceinline__ void storeC(u16* C, size_t idx, float v)   { C[idx] = f2b(v); }
__device__ __forceinline__ void storeC(float* C, size_t idx, float v) { C[idx] = v; }

// =====================================================================
// fp32 -> bf16 conversion prepass
// =====================================================================
__global__ __launch_bounds__(256) void cvt_f32_bf16(
    const float* __restrict__ s, u16* __restrict__ d, int n8)
{
    int i = blockIdx.x * 256 + threadIdx.x;
    if (i >= n8) return;
    const float4* sp = (const float4*)s + (size_t)i * 2;
    float4 a = sp[0], b = sp[1];
    u16 t[8] = { f2b(a.x), f2b(a.y), f2b(a.z), f2b(a.w),
                 f2b(b.x), f2b(b.y), f2b(b.z), f2b(b.w) };
    ((uint4*)d)[i] = *(uint4*)t;
}

__global__ __launch_bounds__(256) void cvt3_f32_bf16(
    const float* __restrict__ a, const float* __restrict__ b,
    const float* __restrict__ c, u16* __restrict__ d, int n8)
{
    const float* s = (blockIdx.y == 0) ? a : ((blockIdx.y == 1) ? b : c);
    u16* dd = d + (size_t)blockIdx.y * n8 * 8;
    int i = blockIdx.x * 256 + threadIdx.x;
    if (i >= n8) return;
    const float4* sp = (const float4*)s + (size_t)i * 2;
    float4 x = sp[0], y = sp[1];
    u16 t[8] = { f2b(x.x), f2b(x.y), f2b(x.z), f2b(x.w),
                 f2b(y.x), f2b(y.y), f2b(y.z), f2b(y.w) };
    ((uint4*)dd)[i] = *(uint4*)t;
}

// =====================================================================
// GEMM: C[M,N] = A[M,K] @ Bt[N,K]^T  (bf16 in, fp32 acc)
// TBM in {128, 64}: row-tile height (BN fixed 128). TBM=64 doubles grid for
// occupancy-starved shapes (final GEMM N=1024 was 2 blocks/CU at TBM=128).
// =====================================================================
template <int TBM, typename TC>
__global__ __launch_bounds__(256) void gemm_bt(
    const u16* __restrict__ A, const u16* __restrict__ Bt, TC* __restrict__ C,
    int M, int Nc, int K)
{
    constexpr int FI = TBM / 32;   // row-frags per wave
    __shared__ alignas(16) u16 As[TBM * 32];
    __shared__ alignas(16) u16 Bs[128 * 32];

    const int tid  = threadIdx.x;
    const int wave = tid >> 6;
    const int lane = tid & 63;
    const int quad = lane >> 4;
    const int lrow = lane & 15;
    const int bm = blockIdx.y * TBM;
    const int bn = blockIdx.x * 128;
    const int wm = (wave & 1) * (TBM / 2);
    const int wn = (wave >> 1) * 64;

    f32x4 acc[FI][4] = {};

    for (int k0 = 0; k0 < K; k0 += 32) {
#if HAS_GLL
        for (int p = 0; p < TBM / 64; ++p) {
            int cbase = wave * TBM + p * 64;       // wave-uniform
            int cme   = cbase + lane;
            int row = cme >> 2, col = (cme & 3) * 8;
            gl_lds16(&A[(size_t)(bm + row) * K + k0 + col], &As[(size_t)cbase * 8]);
        }
        for (int p = 0; p < 2; ++p) {
            int cbase = wave * 128 + p * 64;
            int cme   = cbase + lane;
            int row = cme >> 2, col = (cme & 3) * 8;
            gl_lds16(&Bt[(size_t)(bn + row) * K + k0 + col], &Bs[(size_t)cbase * 8]);
        }
#else
        for (int p = 0; p < TBM / 64; ++p) {
            int idx = p * 256 + tid, row = idx >> 2, col = (idx & 3) * 8;
            *(uint4*)&As[row * 32 + col] = *(const uint4*)&A[(size_t)(bm + row) * K + k0 + col];
        }
        for (int p = 0; p < 2; ++p) {
            int idx = p * 256 + tid, row = idx >> 2, col = (idx & 3) * 8;
            *(uint4*)&Bs[row * 32 + col] = *(const uint4*)&Bt[(size_t)(bn + row) * K + k0 + col];
        }
#endif
        __syncthreads();

        bfrag af[FI], bfv[4];
        for (int i = 0; i < FI; ++i)
            af[i] = *(const bfrag*)&As[(wm + i * 16 + lrow) * 32 + quad * 8];
        for (int j = 0; j < 4; ++j)
            bfv[j] = *(const bfrag*)&Bs[(wn + j * 16 + lrow) * 32 + quad * 8];

        for (int i = 0; i < FI; ++i)
            for (int j = 0; j < 4; ++j)
                acc[i][j] = __builtin_amdgcn_mfma_f32_16x16x32_bf16(af[i], bfv[j], acc[i][j], 0, 0, 0);
        __syncthreads();
    }

    for (int i = 0; i < FI; ++i)
        for (int j = 0; j < 4; ++j)
            for (int r = 0; r < 4; ++r) {
                int row = bm + wm + i * 16 + quad * 4 + r;
                int col = bn + wn + j * 16 + lrow;
                storeC(C, (size_t)row * Nc + col, acc[i][j][r]);
            }
}

// =====================================================================
// Encode via MFMA: enc[b,h,n,m] = tanh( Qh[n,:] @ Wenc[h][:,m] )
// Wenc staged transposed [m][d] as hi/lo bf16 pair (fp32-accurate product).
// Block: 128 tokens of one (b,h); handles Q then K reusing the X tile.
// grid (SEQ/128=16, B*H=64). q_enc pre-scaled by QSCALE.
// =====================================================================
__global__ __launch_bounds__(256) void encode_mfma(
    const u16* __restrict__ QKV, const float* __restrict__ Wenc,
    u16* __restrict__ qe, u16* __restrict__ ke)
{
    const int nt = blockIdx.x;
    const int bh = blockIdx.y;
    const int b = bh >> 4, h = bh & 15;
    const int tid = threadIdx.x;
    const int wave = tid >> 6, lane = tid & 63, quad = lane >> 4, lrow = lane & 15;

    __shared__ alignas(16) u16 Wh[32 * 72];   // [m][d] pad 72
    __shared__ alignas(16) u16 Wl[32 * 72];
    __shared__ alignas(16) u16 Xt[128 * 72];  // [tok][d] pad 72

    // stage Wenc: transpose d-major -> m-major, hi/lo split
    for (int p = 0; p < 8; ++p) {
        int d = p * 8 + (tid >> 5);
        int m = tid & 31;
        float w = Wenc[(size_t)h * (HD * MB) + d * MB + m];
        u16 hi = f2b(w);
        u16 lo = f2b(w - b2f(hi));
        Wh[m * 72 + d] = hi;
        Wl[m * 72 + d] = lo;
    }
    __syncthreads();

    bfrag bhf[2][2], blf[2][2];
    for (int n2 = 0; n2 < 2; ++n2)
        for (int kc = 0; kc < 2; ++kc) {
            bhf[n2][kc] = *(const bfrag*)&Wh[(n2 * 16 + lrow) * 72 + kc * 32 + quad * 8];
            blf[n2][kc] = *(const bfrag*)&Wl[(n2 * 16 + lrow) * 72 + kc * 32 + quad * 8];
        }

    const f32x4 zero = {0.f, 0.f, 0.f, 0.f};
    for (int src = 0; src < 2; ++src) {
        __syncthreads();   // Xt reuse guard
        const u16* base = QKV + (size_t)(b * SEQ + nt * 128) * QKVW + src * DM + h * HD;
        for (int p = 0; p < 4; ++p) {
            int idx = p * 256 + tid;
            int row = idx >> 3, cc = idx & 7;
            *(uint4*)&Xt[row * 72 + cc * 8] = *(const uint4*)&base[(size_t)row * QKVW + cc * 8];
        }
        __syncthreads();

        u16* dst = (src ? ke : qe) + ((size_t)bh * SEQ + (size_t)nt * 128) * MB;
        for (int i = 0; i < 2; ++i) {
            bfrag af[2];
            for (int kc = 0; kc < 2; ++kc)
                af[kc] = *(const bfrag*)&Xt[(wave * 32 + i * 16 + lrow) * 72 + kc * 32 + quad * 8];
            for (int n2 = 0; n2 < 2; ++n2) {
                f32x4 acc = zero;
                for (int kc = 0; kc < 2; ++kc) {
                    acc = __builtin_amdgcn_mfma_f32_16x16x32_bf16(af[kc], bhf[n2][kc], acc, 0, 0, 0);
                    acc = __builtin_amdgcn_mfma_f32_16x16x32_bf16(af[kc], blf[n2][kc], acc, 0, 0, 0);
                }
                for (int r = 0; r < 4; ++r) {
                    float e = EXP2(acc[r] * TWOLOG2E);
                    float t = 1.f - 2.f / (e + 1.f);
                    if (!src) t *= QSCALE;
                    int tok = wave * 32 + i * 16 + quad * 4 + r;
                    dst[(size_t)tok * MB + n2 * 16 + lrow] = f2b(t);
                }
            }
        }
    }
}

// =====================================================================
// Transpose V cols of QKV [S, 3072] -> Vt [B*H*64, 2048]
// =====================================================================
__global__ __launch_bounds__(256) void transpose_v(
    const u16* __restrict__ QKV, u16* __restrict__ Vt)
{
    const int nt = blockIdx.x, h = blockIdx.y, b = blockIdx.z;
    __shared__ alignas(16) u16 tile[64][72];
    const int tid = threadIdx.x;

    for (int p = 0; p < 2; ++p) {
        int idx = p * 256 + tid;
        int t  = idx >> 3;
        int dc = (idx & 7) * 8;
        *(uint4*)&tile[t][dc] =
            *(const uint4*)&QKV[(size_t)(b * SEQ + nt * 64 + t) * QKVW + 2 * DM + h * HD + dc];
    }
    __syncthreads();
    for (int p = 0; p < 2; ++p) {
        int idx = p * 256 + tid;
        int d  = idx >> 3;
        int tc = (idx & 7) * 8;
        u16 tmp[8];
        for (int j = 0; j < 8; ++j) tmp[j] = tile[tc + j][d];
        *(uint4*)&Vt[(size_t)((b * NH + h) * HD + d) * SEQ + nt * 64 + tc] = *(uint4*)tmp;
    }
}

// =====================================================================
// Flash attention v6: block = 128q x all keys; wave = 32q.
// - Kt staged via global_load_lds (contiguous 4KB copy, [key][32] unpadded;
//   kf b128 reads audited to bank-minimum).
// - Vtile staged via global_load_lds with XOR chunk swizzle applied on the
//   GLOBAL read address (dest stays lane-ordered): Vtile[d][c] holds global
//   chunk c^(d&7); vf reads audited to bank-minimum.
// - P: truncating pack, per-(wave,f) padded-72 buffers (audited minimum).
// - den via MFMA-with-ones (exact normalization of truncated P).
// grid (h, b, qt): 1024 blocks = 4/CU; same-h blocks share an XCD.
// =====================================================================
__global__ __launch_bounds__(256) void flash_attn(
    const u16* __restrict__ qe,   // [B,H,N,32], pre-scaled
    const u16* __restrict__ ke,   // [B,H,N,32]
    const u16* __restrict__ Vt,   // [B*H*64, 2048]
    u16* __restrict__ AO)         // [S, 1024]
{
    const int h = blockIdx.x, b = blockIdx.y, qt = blockIdx.z;
    const int tid  = threadIdx.x;
    const int wave = tid >> 6;
    const int lane = tid & 63;
    const int quad = lane >> 4;
    const int lrow = lane & 15;

    __shared__ alignas(16) u16 Kt[64 * 32];       //  4 KB [key][m], contiguous
    __shared__ alignas(16) u16 Vtile[64 * 64];    //  8 KB [d][key-chunk swizzled]
    __shared__ alignas(16) u16 Plds[8][16 * 72];  // 18 KB [wave*2+f][q][key] pad 72

    const size_t bhh = (size_t)(b * NH + h);
    const u16* keb = ke + bhh * SEQ * MB;
    const u16* qeb = qe + bhh * SEQ * MB;
    const u16* vtb = Vt + bhh * HD * SEQ;

    const int q0 = qt * 128 + wave * 32;

    bfrag qf[2];
    for (int f = 0; f < 2; ++f)
        qf[f] = *(const bfrag*)&qeb[(size_t)(q0 + f * 16 + lrow) * MB + quad * 8];

    // hoisted staging source pointers
    const u16* ksrc = keb + tid * 8;                       // += 2048/iter
    const int d0 = wave * 8 + (lane >> 3);
    const int c0 = lane & 7;
    const int g0 = (c0 ^ (d0 & 7)) * 8;                    // (d0+32)&7 == d0&7
    const u16* vsrc0 = vtb + (size_t)d0 * SEQ + g0;        // += 64/iter
    const u16* vsrc1 = vtb + (size_t)(d0 + 32) * SEQ + g0;

    const bfrag ones = __builtin_bit_cast(bfrag,
        (uint4){0x3f803f80u, 0x3f803f80u, 0x3f803f80u, 0x3f803f80u});
    const f32x4 zero = {0.f, 0.f, 0.f, 0.f};

    f32x4 O[2][4] = {};   // [f][j]: D[q=quad*4+r][d=j*16+lrow]
    f32x4 den[2] = {};
    const int sw = lrow & 7;

    for (int c = 0; c < 32; ++c) {
        __syncthreads();   // readers of previous tile done
#if HAS_GLL
        gl_lds16(ksrc,  Kt + wave * 512);
        gl_lds16(vsrc0, Vtile + wave * 512);
        gl_lds16(vsrc1, Vtile + 2048 + wave * 512);
#else
        *(uint4*)&Kt[tid * 8] = *(const uint4*)ksrc;
        *(uint4*)&Vtile[d0 * 64 + c0 * 8] = *(const uint4*)vsrc0;
        *(uint4*)&Vtile[(d0 + 32) * 64 + c0 * 8] = *(const uint4*)vsrc1;
#endif
        ksrc += 64 * MB;
        vsrc0 += 64;
        vsrc1 += 64;
        __syncthreads();   // drains vmcnt -> tiles visible

        bfrag kf[4];
        for (int t = 0; t < 4; ++t)
            kf[t] = *(const bfrag*)&Kt[(t * 16 + lrow) * 32 + quad * 8];

        bfrag pf[2][2];
        for (int f = 0; f < 2; ++f) {
            u16* P = Plds[wave * 2 + f];
            f32x4 St[4];
            for (int t = 0; t < 4; ++t)
                St[t] = __builtin_amdgcn_mfma_f32_16x16x32_bf16(kf[t], qf[f], zero, 0, 0, 0);
            for (int t = 0; t < 4; ++t) {
                float e0 = EXP2(St[t][0]);
                float e1 = EXP2(St[t][1]);
                float e2 = EXP2(St[t][2]);
                float e3 = EXP2(St[t][3]);
                uint2 pk = { packt(e0, e1), packt(e2, e3) };
                *(uint2*)&P[lrow * 72 + t * 16 + quad * 4] = pk;
            }
            for (int h2 = 0; h2 < 2; ++h2)
                pf[f][h2] = *(const bfrag*)&P[lrow * 72 + h2 * 32 + quad * 8];
        }

        for (int f = 0; f < 2; ++f)
            for (int h2 = 0; h2 < 2; ++h2)
                den[f] = __builtin_amdgcn_mfma_f32_16x16x32_bf16(pf[f][h2], ones, den[f], 0, 0, 0);

        for (int j = 0; j < 4; ++j) {
            const u16* vrow = &Vtile[(j * 16 + lrow) * 64];
            bfrag vf0 = *(const bfrag*)&vrow[((quad)     ^ sw) * 8];
            bfrag vf1 = *(const bfrag*)&vrow[((4 + quad) ^ sw) * 8];
            for (int f = 0; f < 2; ++f) {
                O[f][j] = __builtin_amdgcn_mfma_f32_16x16x32_bf16(pf[f][0], vf0, O[f][j], 0, 0, 0);
                O[f][j] = __builtin_amdgcn_mfma_f32_16x16x32_bf16(pf[f][1], vf1, O[f][j], 0, 0, 0);
            }
        }
    }

    for (int f = 0; f < 2; ++f)
        for (int r = 0; r < 4; ++r) {
            float inv = 1.0f / den[f][r];
            size_t rowbase = (size_t)(b * SEQ + q0 + f * 16 + quad * 4 + r) * DM + h * HD;
            for (int j = 0; j < 4; ++j)
                AO[rowbase + j * 16 + lrow] = f2b(O[f][j][r] * inv);
        }
}

// =====================================================================
extern "C" void kernel_launch(void* const* d_in, const int* in_sizes, int n_in,
                              void* d_out, int out_size, void* d_ws, size_t ws_size,
                              hipStream_t stream) {
    const float* x    = (const float*)d_in[0];
    const float* Wq   = (const float*)d_in[1];
    const float* Wk   = (const float*)d_in[2];
    const float* Wv   = (const float*)d_in[3];
    const float* Wenc = (const float*)d_in[4];
    const float* Wo   = (const float*)d_in[5];
    float* out = (float*)d_out;

    const size_t MB1 = (size_t)1024 * 1024;
    char* ws = (char*)d_ws;
    u16* QKV = (u16*)(ws);            // 48M: [8192][3072]
    u16* qe  = (u16*)(ws + 48 * MB1); // 8M  [B,H,N,32]
    u16* ke  = (u16*)(ws + 56 * MB1); // 8M
    u16* AO   = (u16*)(ws);           // overlays dead QKV
    u16* Wo_b = (u16*)(ws + 16 * MB1);

    u16* xb  = (u16*)d_out;                     // 16M bf16 x (d_out scratch)
    u16* w3b = (u16*)((char*)d_out + 16 * MB1); // 6M [Wq;Wk;Wv] bf16
    u16* Vt  = (u16*)d_out;                     // 16M, after xb dead

    cvt_f32_bf16<<<dim3(STOK * DM / 8 / 256), 256, 0, stream>>>(x, xb, STOK * DM / 8);
    cvt3_f32_bf16<<<dim3(DM * DM / 8 / 256, 3), 256, 0, stream>>>(Wq, Wk, Wv, w3b, DM * DM / 8);

    gemm_bt<128, u16><<<dim3(QKVW / 128, STOK / 128), 256, 0, stream>>>(xb, w3b, QKV, STOK, QKVW, DM);

    encode_mfma<<<dim3(SEQ / 128, BATCH * NH), 256, 0, stream>>>(QKV, Wenc, qe, ke);
    transpose_v<<<dim3(SEQ / 64, NH, BATCH), 256, 0, stream>>>(QKV, Vt);
    cvt_f32_bf16<<<dim3(DM * DM / 8 / 256), 256, 0, stream>>>(Wo, Wo_b, DM * DM / 8);

    flash_attn<<<dim3(NH, BATCH, SEQ / 128), 256, 0, stream>>>(qe, ke, Vt, AO);

    gemm_bt<64, float><<<dim3(DM / 128, STOK / 64), 256, 0, stream>>>(AO, Wo_b, out, STOK, DM, DM);
}